// Round 2
// baseline (718.923 us; speedup 1.0000x reference)
//
#include <hip/hip_runtime.h>

#define BN 8
#define NN 512
#define FIN 128
#define FOUT 64
#define ALPHA 0.2f

// Kernel 1: Wh[b,n,o] = sum_i h[b,n,i] * W[i,o]; e_i[bn] = Wh·a_i; e_j[bn] = Wh·a_j
__global__ __launch_bounds__(64) void wh_kernel(
    const float* __restrict__ h, const float* __restrict__ W,
    const float* __restrict__ a,
    float* __restrict__ Wh, float* __restrict__ e_i, float* __restrict__ e_j) {
    int bn = blockIdx.x;          // 0..4095
    int o  = threadIdx.x;         // 0..63
    __shared__ float hrow[FIN];
    hrow[o]      = h[bn * FIN + o];
    hrow[o + 64] = h[bn * FIN + 64 + o];
    __syncthreads();
    float acc = 0.f;
#pragma unroll 8
    for (int i = 0; i < FIN; ++i)
        acc = fmaf(hrow[i], W[i * FOUT + o], acc);   // W reads coalesced, L1/L2-resident
    Wh[bn * FOUT + o] = acc;
    float pi = acc * a[o];
    float pj = acc * a[FOUT + o];
#pragma unroll
    for (int off = 32; off >= 1; off >>= 1) {
        pi += __shfl_xor(pi, off, 64);
        pj += __shfl_xor(pj, off, 64);
    }
    if (o == 0) { e_i[bn] = pi; e_j[bn] = pj; }
}

// Kernel 2: pure streaming score computation. No LDS, no barriers.
// Block = half a row (256 j's of one (b,i)); 8192 blocks total.
// s[b,i,j] = leaky(e_i[bi] + e_j[bj] + a_e * (edge[b,i,j,:]·U))
__global__ __launch_bounds__(256) void score_kernel(
    const float* __restrict__ edge, const float* __restrict__ U,
    const float* __restrict__ a,
    const float* __restrict__ e_i, const float* __restrict__ e_j,
    float* __restrict__ sws) {
    int idx  = blockIdx.x;        // 0..8191
    int bi   = idx >> 1;
    int half = idx & 1;
    int b    = bi >> 9;
    int tid  = threadIdx.x;
    int lane = tid & 63;
    int wave = tid >> 6;
    int sub  = lane & 15;

    float4 Uv  = ((const float4*)U)[sub];
    float  a_e = a[2 * FOUT];
    float  eiv = e_i[bi];
    const float4* erow = (const float4*)(edge + (size_t)bi * (NN * FOUT));
    const float*  ejb  = e_j + (b << 9);
    float*        srow = sws + (size_t)bi * NN;

    int jofs = (half << 8) + (wave << 2) + (lane >> 4);   // this lane's j offset
#pragma unroll 8
    for (int it = 0; it < 16; ++it) {
        int j = (it << 4) + jofs;
        float4 ef = erow[(j << 4) + sub];    // wave reads 1 KiB contiguous
        float p = fmaf(ef.x, Uv.x, fmaf(ef.y, Uv.y, fmaf(ef.z, Uv.z, ef.w * Uv.w)));
        p += __shfl_xor(p, 1, 16);
        p += __shfl_xor(p, 2, 16);
        p += __shfl_xor(p, 4, 16);
        p += __shfl_xor(p, 8, 16);
        float s = eiv + ejb[j] + a_e * p;    // ejb broadcast within 16-lane group
        s = (s >= 0.f) ? s : (ALPHA * s);
        // gather the wave's 4 results to lanes 0..3 for one coalesced 16B store
        float v = __shfl(s, (lane & 3) << 4, 64);
        if (lane < 4)
            srow[(it << 4) + (half << 8) + (wave << 2) + lane] = v;
    }
}

// Kernel 3: per (b,i): softmax over precomputed s row, then out = p · Wh[b]
__global__ __launch_bounds__(256) void soft_mv_kernel(
    const float* __restrict__ sws, const float* __restrict__ Wh,
    float* __restrict__ out) {
    int bi   = blockIdx.x;        // b*NN + i
    int b    = bi >> 9;
    int tid  = threadIdx.x;
    int lane = tid & 63;
    int wave = tid >> 6;

    __shared__ float p_lds[NN];
    __shared__ float red[8];
    __shared__ float accbuf[4][FOUT];

    const float* srow = sws + (size_t)bi * NN;
    float s0 = srow[tid];
    float s1 = srow[tid + 256];

    float m = fmaxf(s0, s1);
#pragma unroll
    for (int off = 32; off >= 1; off >>= 1) m = fmaxf(m, __shfl_xor(m, off, 64));
    if (lane == 0) red[wave] = m;
    __syncthreads();
    m = fmaxf(fmaxf(red[0], red[1]), fmaxf(red[2], red[3]));
    float v0 = expf(s0 - m);
    float v1 = expf(s1 - m);
    float ssum = v0 + v1;
    p_lds[tid]       = v0;
    p_lds[tid + 256] = v1;
#pragma unroll
    for (int off = 32; off >= 1; off >>= 1) ssum += __shfl_xor(ssum, off, 64);
    if (lane == 0) red[4 + wave] = ssum;
    __syncthreads();
    float inv = 1.0f / (red[4] + red[5] + red[6] + red[7]);

    // out[o] = inv * sum_j p_j * Wh[b,j,o]   (Wh 1 MiB, L2-resident)
    int o = tid & 63, chunk = tid >> 6;
    const float* WhB = Wh + (((size_t)b) << 9) * FOUT;
    float acc = 0.f;
    int j0 = chunk << 7;
#pragma unroll 8
    for (int j = j0; j < j0 + 128; ++j)
        acc = fmaf(p_lds[j], WhB[(j << 6) + o], acc);   // lanes=o coalesced, p_lds broadcast
    accbuf[chunk][o] = acc;
    __syncthreads();
    if (chunk == 0) {
        float r = (accbuf[0][o] + accbuf[1][o] + accbuf[2][o] + accbuf[3][o]) * inv;
        out[((size_t)bi << 6) + o] = r;
    }
}

extern "C" void kernel_launch(void* const* d_in, const int* in_sizes, int n_in,
                              void* d_out, int out_size, void* d_ws, size_t ws_size,
                              hipStream_t stream) {
    const float* h    = (const float*)d_in[0];   // (8,512,128)
    const float* edge = (const float*)d_in[1];   // (8,512,512,64)
    const float* W    = (const float*)d_in[2];   // (1,128,64)
    const float* U    = (const float*)d_in[3];   // (1,64)
    const float* a    = (const float*)d_in[4];   // (1,129)
    float* out = (float*)d_out;                  // (8,512,64)

    float* Wh  = (float*)d_ws;                   // 262144 floats
    float* e_i = Wh + BN * NN * FOUT;            // 4096
    float* e_j = e_i + BN * NN;                  // 4096
    float* sws = e_j + BN * NN;                  // 8*512*512 floats = 8 MiB

    wh_kernel<<<BN * NN, 64, 0, stream>>>(h, W, a, Wh, e_i, e_j);
    score_kernel<<<BN * NN * 2, 256, 0, stream>>>(edge, U, a, e_i, e_j, sws);
    soft_mv_kernel<<<BN * NN, 256, 0, stream>>>(sws, Wh, out);
}